// Round 11
// baseline (211.107 us; speedup 1.0000x reference)
//
#include <hip/hip_runtime.h>

// B=16, T=1024, N=1024, D=256, WIN=64
// outputs (flat): R (B,T,2D) = [A@V, Q]   : 8388608 f32
//                 alignments (B,N,T) = A^T: 16777216 f32
//                 max_att (B,T)           : 16384 f32
//
// v16 (RESUBMIT — R10 bench was an infra failure, kernel never ran)
// v16 = v14b (158.7us best; nt stores) + 4-slice K staging -> 7 blocks/CU.
//   v12 (same occupancy) failed for two reasons that are BOTH fixed now:
//   (1) write-allocate L2 thrash evicting K/V windows -> nt stores bypass L2;
//   (2) scattered 16B register-strip stores -> partial-sector RMW write
//       amplification -> barrier transpose writes contiguous 64B lines.
//   So this is the clean retest of high occupancy:
//  - ks[64][68] = 17.4KB (68%32==4, v12-measured 0 conflicts) + p_lds 4.4KB
//    = 21.8KB -> 7 blocks/CU = 1792 slots >= 1264-block grid: single cohort,
//    zero-drain fully overlapped, 7 attn blocks/CU cover barrier drains.
//  - staging is pow2: r=idx>>4, c=idx&15, exactly 4 unguarded loads/thread
//    per slice (v15's div/mod + guard tax eliminated).
//  - everything else v14b verbatim (nt stores, strip transpose, zeros-first
//    roles, hoisted Q copy). v12 passed absmax 0.00195 with this grouping.

#define BB 16
#define TT 1024
#define NN 1024
#define DD 256
#define WIN 64
#define TBLK 16          // queries per attn block
#define NT 256           // 4 waves, 4 queries each
#define NZ 240           // zero-streaming blocks (16 batches x 15)

#define R_ELEMS   (16u*1024u*512u)        // 8388608
#define ALN_ELEMS (16u*1024u*1024u)       // 16777216

#define LSTR 68          // LDS row stride (dwords); 68%32==4 -> conflict-free b128

typedef float f32x4 __attribute__((ext_vector_type(4)));

__device__ __forceinline__ void nts4(void* p, float4 v) {
    f32x4 nv;
    nv.x = v.x; nv.y = v.y; nv.z = v.z; nv.w = v.w;
    __builtin_nontemporal_store(nv, (f32x4*)p);
}

__global__ __launch_bounds__(NT, 7) void attn_v16(
    const float* __restrict__ Q, const float* __restrict__ K,
    const float* __restrict__ V, const int* __restrict__ prev_in,
    float* __restrict__ out)
{
    __shared__ float ks[WIN * LSTR];        // 17408 B: K slice (64 rows x 64d)
    __shared__ float p_lds[TBLK][WIN + 4];  //  4352 B: probabilities [t][j]

    float* Rout   = out;
    float* aligns = out + R_ELEMS;
    float* maxatt = out + R_ELEMS + ALN_ELEMS;

    const int tid = threadIdx.x;

    // ================= role 1: zero-streaming blocks =================
    if (blockIdx.x < NZ) {
        const int zb    = blockIdx.x;
        const int b     = zb / 15;          // 15 blocks per batch
        const int chunk = zb % 15;          // 64 rows each
        const int prev  = prev_in[b];
        float* zbase = aligns + (size_t)b * NN * TT;
        const float4 z = make_float4(0.f, 0.f, 0.f, 0.f);
        #pragma unroll 8
        for (int r = 0; r < 64; ++r) {
            int idx = chunk * 64 + r;          // 0..959 among non-window rows
            int n   = idx < prev ? idx : idx + WIN;
            nts4(zbase + (size_t)n * 1024 + tid * 4, z);  // nt: no L2 allocation
        }
        return;                                // stores drain under attn compute
    }

    // ================= role 2: attention blocks =================
    const int aid  = blockIdx.x - NZ;
    const int lane = tid & 63;
    const int w    = __builtin_amdgcn_readfirstlane(tid >> 6);  // wave 0..3
    const int b    = aid >> 6;              // 64 blocks per batch
    const int t0   = (aid & 63) * TBLK;
    const int prev = prev_in[b];

    const float* qb = Q + ((size_t)b * TT + t0 + 4 * w) * DD;   // wave-uniform base

    // ---- hoisted Q copy (nt store: R never re-read) ----
    #pragma unroll
    for (int t = 0; t < 4; ++t) {
        float4 qv = ((const float4*)(qb + t * DD))[lane];
        float* Rrow = Rout + ((size_t)b * TT + t0 + 4 * w + t) * (2 * DD);
        nts4(Rrow + DD + lane * 4, qv);
    }

    // ============ QK^T over four 64-dim slices (pow2 staging) ============
    float acc[4] = {0.f, 0.f, 0.f, 0.f};
    #pragma unroll
    for (int s = 0; s < 4; ++s) {
        if (s) __syncthreads();             // previous slice's readers done
        const float4* Ksrc = (const float4*)(K + ((size_t)b * NN + prev) * DD + s * 64);
        #pragma unroll
        for (int k = 0; k < 4; ++k) {
            int idx = tid + k * NT;         // 0..1023 float4 chunks
            int r = idx >> 4, c = idx & 15; // row 0..63, col-chunk 0..15
            float4 v = Ksrc[(size_t)r * 64 + c];
            *(float4*)&ks[r * LSTR + c * 4] = v;
        }
        __syncthreads();

        const float* qh = qb + s * 64;
        #pragma unroll
        for (int d4 = 0; d4 < 16; ++d4) {
            float4 kk = *(const float4*)&ks[lane * LSTR + d4 * 4];  // conflict-free b128
            #pragma unroll
            for (int t = 0; t < 4; ++t) {
                float4 q = ((const float4*)(qh + t * DD))[d4];      // wave-uniform
                acc[t] = fmaf(q.x, kk.x, fmaf(q.y, kk.y, fmaf(q.z, kk.z, fmaf(q.w, kk.w, acc[t]))));
            }
        }
    }

    // ================= softmax + argmax (wave-local), p -> LDS ===========
    #pragma unroll
    for (int t = 0; t < 4; ++t) {
        float v = acc[t] * 0.0625f;         // 1/sqrt(256)

        float m = v;
        #pragma unroll
        for (int off = 32; off; off >>= 1) m = fmaxf(m, __shfl_xor(m, off));

        float e = expf(v - m);
        float s = e;
        #pragma unroll
        for (int off = 32; off; off >>= 1) s += __shfl_xor(s, off);

        p_lds[4 * w + t][lane] = e / s;

        float av = v; int ai = lane;
        #pragma unroll
        for (int off = 32; off; off >>= 1) {
            float ov = __shfl_xor(av, off);
            int   oi = __shfl_xor(ai, off);
            if (ov > av || (ov == av && oi < ai)) { av = ov; ai = oi; }
        }
        if (lane == 0)
            __builtin_nontemporal_store((float)(prev + ai),
                                        &maxatt[(size_t)b * TT + t0 + 4 * w + t]);
    }
    __syncthreads();                        // all 16 p rows visible

    // ===== window-row alignment strip: 64 rows x 16 floats (64B lines) ====
    // Zero blocks never touch these rows -> written exactly once.
    {
        const int j = tid >> 2, cg = tid & 3;
        float4 v;
        v.x = p_lds[cg * 4 + 0][j];
        v.y = p_lds[cg * 4 + 1][j];
        v.z = p_lds[cg * 4 + 2][j];
        v.w = p_lds[cg * 4 + 3][j];
        nts4(aligns + ((size_t)b * NN + prev + j) * TT + t0 + cg * 4, v);
    }

    // ================= PV direct from global (L2-hot V) ==================
    // lane = d-chunk (64 x float4 = 256 d); reads own wave's p rows.
    {
        const float4* V4 = (const float4*)(V + ((size_t)b * NN + prev) * DD);
        float4 o[4];
        #pragma unroll
        for (int t = 0; t < 4; ++t) o[t] = make_float4(0.f, 0.f, 0.f, 0.f);

        #pragma unroll 4
        for (int j4 = 0; j4 < WIN / 4; ++j4) {
            float4 p0 = *(const float4*)&p_lds[4 * w + 0][j4 * 4];  // uniform bcast
            float4 p1 = *(const float4*)&p_lds[4 * w + 1][j4 * 4];
            float4 p2 = *(const float4*)&p_lds[4 * w + 2][j4 * 4];
            float4 p3 = *(const float4*)&p_lds[4 * w + 3][j4 * 4];
            float4 v0 = V4[(size_t)(j4 * 4 + 0) * 64 + lane];
            float4 v1 = V4[(size_t)(j4 * 4 + 1) * 64 + lane];
            float4 v2 = V4[(size_t)(j4 * 4 + 2) * 64 + lane];
            float4 v3 = V4[(size_t)(j4 * 4 + 3) * 64 + lane];
            #define ACC4(o_, p_) \
                o_.x = fmaf(p_.x, v0.x, fmaf(p_.y, v1.x, fmaf(p_.z, v2.x, fmaf(p_.w, v3.x, o_.x)))); \
                o_.y = fmaf(p_.x, v0.y, fmaf(p_.y, v1.y, fmaf(p_.z, v2.y, fmaf(p_.w, v3.y, o_.y)))); \
                o_.z = fmaf(p_.x, v0.z, fmaf(p_.y, v1.z, fmaf(p_.z, v2.z, fmaf(p_.w, v3.z, o_.z)))); \
                o_.w = fmaf(p_.x, v0.w, fmaf(p_.y, v1.w, fmaf(p_.z, v2.w, fmaf(p_.w, v3.w, o_.w))));
            ACC4(o[0], p0) ACC4(o[1], p1) ACC4(o[2], p2) ACC4(o[3], p3)
            #undef ACC4
        }

        #pragma unroll
        for (int t = 0; t < 4; ++t) {
            float* Rrow = Rout + ((size_t)b * TT + t0 + 4 * w + t) * (2 * DD);
            nts4(Rrow + lane * 4, o[t]);    // A@V (Q half already written)
        }
    }
}

extern "C" void kernel_launch(void* const* d_in, const int* in_sizes, int n_in,
                              void* d_out, int out_size, void* d_ws, size_t ws_size,
                              hipStream_t stream) {
    const float* Q = (const float*)d_in[0];
    const float* K = (const float*)d_in[1];
    const float* V = (const float*)d_in[2];
    const int* prev = (const int*)d_in[3];
    float* out = (float*)d_out;

    // single launch: 240 zero-streaming blocks first, then 1024 attn blocks;
    // whole 1264-block grid resident in one cohort at 7 blocks/CU.
    attn_v16<<<NZ + BB * TT / TBLK, NT, 0, stream>>>(Q, K, V, prev, out);
}

// Round 12
// 193.232 us; speedup vs baseline: 1.0925x; 1.0925x over previous
//
#include <hip/hip_runtime.h>

// B=16, T=1024, N=1024, D=256, WIN=64
// outputs (flat): R (B,T,2D) = [A@V, Q]   : 8388608 f32
//                 alignments (B,N,T) = A^T: 16777216 f32
//                 max_att (B,T)           : 16384 f32
//
// v17 = v14b (158.7us champion) + ONE lever: d-split cooperative PV.
//   v16 refuted the L2-policy theory of the high-occupancy explosions:
//   7 blocks/CU thrashes per-XCD L2 regardless of nt stores (FETCH 118MB,
//   WRITE 184MB = v12's signature). Occupancy >4 blocks/CU is dead.
//   Remaining mechanism: v14b's PV has each of 4 waves stream the FULL
//   64KB V window from L2 -> 1MB L2 reads per CU ~= 7.5us at 135GB/s/CU,
//   vs ~3.4us of PV VALU: PV is L2-BW-bound.
//   Fix: after the existing post-softmax barrier (all 16 p rows already
//   visible for the strip), wave w computes ALL 16 queries for d-quarter
//   [64w,64w+64). lane=(jj,d4); each lane covers 16 V rows -> per-wave V
//   reads 16KB (4x less), block total 64KB (redundancy 1x).
//   - p_lds b128 reads at 4 addresses/16-lane groups: 2-way bank = free.
//   - jj-reduce: 2 shfl_xor steps (128 shfl+add / lane).
//   - R stores predicated on compile-time t (no runtime reg indexing).
//   No barrier count change, no LDS change, QK/softmax/strip/zeros verbatim.

#define BB 16
#define TT 1024
#define NN 1024
#define DD 256
#define WIN 64
#define TBLK 16          // queries per attn block
#define NT 256           // 4 waves
#define NZ 240           // zero-streaming blocks (16 batches x 15)

#define R_ELEMS   (16u*1024u*512u)        // 8388608
#define ALN_ELEMS (16u*1024u*1024u)       // 16777216

#define LSTR 132         // LDS row stride (dwords); 132%32==4 -> conflict-free b128

typedef float f32x4 __attribute__((ext_vector_type(4)));

__device__ __forceinline__ void nts4(void* p, float4 v) {
    f32x4 nv;
    nv.x = v.x; nv.y = v.y; nv.z = v.z; nv.w = v.w;
    __builtin_nontemporal_store(nv, (f32x4*)p);
}

__global__ __launch_bounds__(NT, 4) void attn_v17(
    const float* __restrict__ Q, const float* __restrict__ K,
    const float* __restrict__ V, const int* __restrict__ prev_in,
    float* __restrict__ out)
{
    __shared__ float ks[WIN * LSTR];        // 33792 B: K half-tile
    __shared__ float p_lds[TBLK][WIN + 4];  // 4352 B : probabilities [t][j]

    float* Rout   = out;
    float* aligns = out + R_ELEMS;
    float* maxatt = out + R_ELEMS + ALN_ELEMS;

    const int tid = threadIdx.x;

    // ================= role 1: zero-streaming blocks =================
    if (blockIdx.x < NZ) {
        const int zb    = blockIdx.x;
        const int b     = zb / 15;          // 15 blocks per batch
        const int chunk = zb % 15;          // 64 rows each
        const int prev  = prev_in[b];
        float* zbase = aligns + (size_t)b * NN * TT;
        const float4 z = make_float4(0.f, 0.f, 0.f, 0.f);
        #pragma unroll 8
        for (int r = 0; r < 64; ++r) {
            int idx = chunk * 64 + r;          // 0..959 among non-window rows
            int n   = idx < prev ? idx : idx + WIN;
            nts4(zbase + (size_t)n * 1024 + tid * 4, z);  // nt stream
        }
        return;                                // stores drain under attn compute
    }

    // ================= role 2: attention blocks (v14b core) ==============
    const int aid  = blockIdx.x - NZ;
    const int lane = tid & 63;
    const int w    = __builtin_amdgcn_readfirstlane(tid >> 6);  // wave 0..3
    const int b    = aid >> 6;              // 64 blocks per batch
    const int t0   = (aid & 63) * TBLK;
    const int prev = prev_in[b];

    const float* qb = Q + ((size_t)b * TT + t0 + 4 * w) * DD;   // wave-uniform base

    // ---- hoisted Q copy (nt store: R never re-read) ----
    #pragma unroll
    for (int t = 0; t < 4; ++t) {
        float4 qv = ((const float4*)(qb + t * DD))[lane];
        float* Rrow = Rout + ((size_t)b * TT + t0 + 4 * w + t) * (2 * DD);
        nts4(Rrow + DD + lane * 4, qv);
    }

    // ================= QK^T over two 128-d halves =================
    float acc[4] = {0.f, 0.f, 0.f, 0.f};
    #pragma unroll
    for (int h = 0; h < 2; ++h) {
        if (h) __syncthreads();             // h0 readers done before restage
        const float4* Ksrc = (const float4*)(K + ((size_t)b * NN + prev) * DD + h * 128);
        #pragma unroll
        for (int k = 0; k < 8; ++k) {
            int t4 = tid + k * NT;          // 0..2047 float4 chunks
            int r = t4 >> 5, c = t4 & 31;
            float4 v = Ksrc[(size_t)r * 64 + c];
            *(float4*)&ks[r * LSTR + c * 4] = v;
        }
        __syncthreads();

        const float* qh = qb + h * 128;
        #pragma unroll 8
        for (int d4 = 0; d4 < 32; ++d4) {
            float4 kk = *(const float4*)&ks[lane * LSTR + d4 * 4];  // conflict-free b128
            #pragma unroll
            for (int t = 0; t < 4; ++t) {
                float4 q = ((const float4*)(qh + t * DD))[d4];      // wave-uniform
                acc[t] = fmaf(q.x, kk.x, fmaf(q.y, kk.y, fmaf(q.z, kk.z, fmaf(q.w, kk.w, acc[t]))));
            }
        }
    }

    // ================= softmax + argmax (wave-local), p -> LDS ===========
    #pragma unroll
    for (int t = 0; t < 4; ++t) {
        float v = acc[t] * 0.0625f;         // 1/sqrt(256)

        float m = v;
        #pragma unroll
        for (int off = 32; off; off >>= 1) m = fmaxf(m, __shfl_xor(m, off));

        float e = expf(v - m);
        float s = e;
        #pragma unroll
        for (int off = 32; off; off >>= 1) s += __shfl_xor(s, off);

        p_lds[4 * w + t][lane] = e / s;

        float av = v; int ai = lane;
        #pragma unroll
        for (int off = 32; off; off >>= 1) {
            float ov = __shfl_xor(av, off);
            int   oi = __shfl_xor(ai, off);
            if (ov > av || (ov == av && oi < ai)) { av = ov; ai = oi; }
        }
        if (lane == 0)
            __builtin_nontemporal_store((float)(prev + ai),
                                        &maxatt[(size_t)b * TT + t0 + 4 * w + t]);
    }
    __syncthreads();                        // all 16 p rows visible (strip + PV)

    // ===== window-row alignment strip: 64 rows x 16 floats (64B lines) ====
    {
        const int j = tid >> 2, cg = tid & 3;
        float4 v;
        v.x = p_lds[cg * 4 + 0][j];
        v.y = p_lds[cg * 4 + 1][j];
        v.z = p_lds[cg * 4 + 2][j];
        v.w = p_lds[cg * 4 + 3][j];
        nts4(aligns + ((size_t)b * NN + prev + j) * TT + t0 + cg * 4, v);
    }

    // ============== PV: d-split cooperative (V read once per block) =========
    // wave w owns d-quarter [64w, 64w+64); lane = jj*16 + d4.
    // lane covers V rows j = jj*16 + k (k=0..15) for its d-chunk d4.
    {
        const int jj = lane >> 4;           // 0..3
        const int d4 = lane & 15;           // 0..15
        const float* Vq = V + ((size_t)b * NN + prev + jj * 16) * DD + w * 64 + d4 * 4;

        float4 o[16];
        #pragma unroll
        for (int t = 0; t < 16; ++t) o[t] = make_float4(0.f, 0.f, 0.f, 0.f);

        #pragma unroll
        for (int k4 = 0; k4 < 4; ++k4) {
            float4 vv0 = *(const float4*)(Vq + (size_t)(k4 * 4 + 0) * DD);
            float4 vv1 = *(const float4*)(Vq + (size_t)(k4 * 4 + 1) * DD);
            float4 vv2 = *(const float4*)(Vq + (size_t)(k4 * 4 + 2) * DD);
            float4 vv3 = *(const float4*)(Vq + (size_t)(k4 * 4 + 3) * DD);
            #pragma unroll
            for (int t = 0; t < 16; ++t) {
                // p_lds[t][jj*16 + k4*4 .. +3]: 4 addrs/64 lanes, 2-way bank (free)
                float4 p4 = *(const float4*)&p_lds[t][jj * 16 + k4 * 4];
                o[t].x = fmaf(p4.x, vv0.x, fmaf(p4.y, vv1.x, fmaf(p4.z, vv2.x, fmaf(p4.w, vv3.x, o[t].x))));
                o[t].y = fmaf(p4.x, vv0.y, fmaf(p4.y, vv1.y, fmaf(p4.z, vv2.y, fmaf(p4.w, vv3.y, o[t].y))));
                o[t].z = fmaf(p4.x, vv0.z, fmaf(p4.y, vv1.z, fmaf(p4.z, vv2.z, fmaf(p4.w, vv3.z, o[t].z))));
                o[t].w = fmaf(p4.x, vv0.w, fmaf(p4.y, vv1.w, fmaf(p4.z, vv2.w, fmaf(p4.w, vv3.w, o[t].w))));
            }
        }

        // reduce partial sums over the 4 jj groups (lane bits 4,5)
        #pragma unroll
        for (int t = 0; t < 16; ++t) {
            o[t].x += __shfl_xor(o[t].x, 16); o[t].x += __shfl_xor(o[t].x, 32);
            o[t].y += __shfl_xor(o[t].y, 16); o[t].y += __shfl_xor(o[t].y, 32);
            o[t].z += __shfl_xor(o[t].z, 16); o[t].z += __shfl_xor(o[t].z, 32);
            o[t].w += __shfl_xor(o[t].w, 16); o[t].w += __shfl_xor(o[t].w, 32);
        }

        // R store: lanes with jj == t>>2 store row t, dims w*64 + d4*4
        // (compile-time t index -> no runtime reg-array indexing; 16 lanes
        //  x 16B = 256B contiguous per predicated store)
        #pragma unroll
        for (int t = 0; t < 16; ++t) {
            if (jj == (t >> 2)) {
                float* Rp = Rout + ((size_t)b * TT + t0 + t) * (2 * DD) + w * 64 + d4 * 4;
                nts4(Rp, o[t]);
            }
        }
    }
}

extern "C" void kernel_launch(void* const* d_in, const int* in_sizes, int n_in,
                              void* d_out, int out_size, void* d_ws, size_t ws_size,
                              hipStream_t stream) {
    const float* Q = (const float*)d_in[0];
    const float* K = (const float*)d_in[1];
    const float* V = (const float*)d_in[2];
    const int* prev = (const int*)d_in[3];
    float* out = (float*)d_out;

    // single launch: 240 zero-streaming blocks first, then 1024 attn blocks
    attn_v17<<<NZ + BB * TT / TBLK, NT, 0, stream>>>(Q, K, V, prev, out);
}

// Round 13
// 156.304 us; speedup vs baseline: 1.3506x; 1.2363x over previous
//
#include <hip/hip_runtime.h>

// B=16, T=1024, N=1024, D=256, WIN=64
// outputs (flat): R (B,T,2D) = [A@V, Q]   : 8388608 f32
//                 alignments (B,N,T) = A^T: 16777216 f32
//                 max_att (B,T)           : 16384 f32
//
// v18 = v14b (158.7us champion) + 2-way d-split PV (spill-free redo of v17).
//   v17 diagnosis: o[16] float4 = 64 acc VGPRs + live vv/p4 > budget ->
//   scratch spill (VGPR_Count=64 impossible otherwise; WRITE +95MB, FETCH
//   +15MB = spill traffic; VALUBusy fell to 12.9%). The PV-L2-BW theory was
//   never tested.
//   v18 sizes the same mechanism to the register file:
//  - wave w owns 8 queries (qg=(w>>1)*8) x 128 dims (dh=w&1).
//    lane = (jj=row-half, d4=0..31). acc o[8] = 32 VGPRs. No spill.
//  - block V reads 128KB (2x redundancy) vs v14b 256KB (4x): halves the
//    ~7.5us/CU PV L2-read time.
//  - jj-reduce: one shfl_xor(32)/component. Stores full-wave: jj-group
//    stores rows qg+jj*4+tt (compile-time acc index, cndmask on jj),
//    two contiguous 512B segments per instruction. No masked partial
//    stores (v17's other risk), no runtime reg indexing.
//  - barriers, QK^T, softmax, strip, zero-roles, nt stores: v14b verbatim.

#define BB 16
#define TT 1024
#define NN 1024
#define DD 256
#define WIN 64
#define TBLK 16          // queries per attn block
#define NT 256           // 4 waves
#define NZ 240           // zero-streaming blocks (16 batches x 15)

#define R_ELEMS   (16u*1024u*512u)        // 8388608
#define ALN_ELEMS (16u*1024u*1024u)       // 16777216

#define LSTR 132         // LDS row stride (dwords); 132%32==4 -> conflict-free b128

typedef float f32x4 __attribute__((ext_vector_type(4)));

__device__ __forceinline__ void nts4(void* p, float4 v) {
    f32x4 nv;
    nv.x = v.x; nv.y = v.y; nv.z = v.z; nv.w = v.w;
    __builtin_nontemporal_store(nv, (f32x4*)p);
}

__global__ __launch_bounds__(NT, 4) void attn_v18(
    const float* __restrict__ Q, const float* __restrict__ K,
    const float* __restrict__ V, const int* __restrict__ prev_in,
    float* __restrict__ out)
{
    __shared__ float ks[WIN * LSTR];        // 33792 B: K half-tile
    __shared__ float p_lds[TBLK][WIN + 4];  // 4352 B : probabilities [t][j]

    float* Rout   = out;
    float* aligns = out + R_ELEMS;
    float* maxatt = out + R_ELEMS + ALN_ELEMS;

    const int tid = threadIdx.x;

    // ================= role 1: zero-streaming blocks =================
    if (blockIdx.x < NZ) {
        const int zb    = blockIdx.x;
        const int b     = zb / 15;          // 15 blocks per batch
        const int chunk = zb % 15;          // 64 rows each
        const int prev  = prev_in[b];
        float* zbase = aligns + (size_t)b * NN * TT;
        const float4 z = make_float4(0.f, 0.f, 0.f, 0.f);
        #pragma unroll 8
        for (int r = 0; r < 64; ++r) {
            int idx = chunk * 64 + r;          // 0..959 among non-window rows
            int n   = idx < prev ? idx : idx + WIN;
            nts4(zbase + (size_t)n * 1024 + tid * 4, z);  // nt stream
        }
        return;                                // stores drain under attn compute
    }

    // ================= role 2: attention blocks (v14b core) ==============
    const int aid  = blockIdx.x - NZ;
    const int lane = tid & 63;
    const int w    = __builtin_amdgcn_readfirstlane(tid >> 6);  // wave 0..3
    const int b    = aid >> 6;              // 64 blocks per batch
    const int t0   = (aid & 63) * TBLK;
    const int prev = prev_in[b];

    const float* qb = Q + ((size_t)b * TT + t0 + 4 * w) * DD;   // wave-uniform base

    // ---- hoisted Q copy (nt store: R never re-read) ----
    #pragma unroll
    for (int t = 0; t < 4; ++t) {
        float4 qv = ((const float4*)(qb + t * DD))[lane];
        float* Rrow = Rout + ((size_t)b * TT + t0 + 4 * w + t) * (2 * DD);
        nts4(Rrow + DD + lane * 4, qv);
    }

    // ================= QK^T over two 128-d halves =================
    float acc[4] = {0.f, 0.f, 0.f, 0.f};
    #pragma unroll
    for (int h = 0; h < 2; ++h) {
        if (h) __syncthreads();             // h0 readers done before restage
        const float4* Ksrc = (const float4*)(K + ((size_t)b * NN + prev) * DD + h * 128);
        #pragma unroll
        for (int k = 0; k < 8; ++k) {
            int t4 = tid + k * NT;          // 0..2047 float4 chunks
            int r = t4 >> 5, c = t4 & 31;
            float4 v = Ksrc[(size_t)r * 64 + c];
            *(float4*)&ks[r * LSTR + c * 4] = v;
        }
        __syncthreads();

        const float* qh = qb + h * 128;
        #pragma unroll 8
        for (int d4 = 0; d4 < 32; ++d4) {
            float4 kk = *(const float4*)&ks[lane * LSTR + d4 * 4];  // conflict-free b128
            #pragma unroll
            for (int t = 0; t < 4; ++t) {
                float4 q = ((const float4*)(qh + t * DD))[d4];      // wave-uniform
                acc[t] = fmaf(q.x, kk.x, fmaf(q.y, kk.y, fmaf(q.z, kk.z, fmaf(q.w, kk.w, acc[t]))));
            }
        }
    }

    // ================= softmax + argmax (wave-local), p -> LDS ===========
    #pragma unroll
    for (int t = 0; t < 4; ++t) {
        float v = acc[t] * 0.0625f;         // 1/sqrt(256)

        float m = v;
        #pragma unroll
        for (int off = 32; off; off >>= 1) m = fmaxf(m, __shfl_xor(m, off));

        float e = expf(v - m);
        float s = e;
        #pragma unroll
        for (int off = 32; off; off >>= 1) s += __shfl_xor(s, off);

        p_lds[4 * w + t][lane] = e / s;

        float av = v; int ai = lane;
        #pragma unroll
        for (int off = 32; off; off >>= 1) {
            float ov = __shfl_xor(av, off);
            int   oi = __shfl_xor(ai, off);
            if (ov > av || (ov == av && oi < ai)) { av = ov; ai = oi; }
        }
        if (lane == 0)
            __builtin_nontemporal_store((float)(prev + ai),
                                        &maxatt[(size_t)b * TT + t0 + 4 * w + t]);
    }
    __syncthreads();                        // all 16 p rows visible (strip + PV)

    // ===== window-row alignment strip: 64 rows x 16 floats (64B lines) ====
    {
        const int j = tid >> 2, cg = tid & 3;
        float4 v;
        v.x = p_lds[cg * 4 + 0][j];
        v.y = p_lds[cg * 4 + 1][j];
        v.z = p_lds[cg * 4 + 2][j];
        v.w = p_lds[cg * 4 + 3][j];
        nts4(aligns + ((size_t)b * NN + prev + j) * TT + t0 + cg * 4, v);
    }

    // ============== PV: 2-way d-split (V read 2x per block, no spill) =======
    // wave w: queries qg..qg+7, dims [dh*128, dh*128+128).
    // lane = jj*32 + d4: jj = row-half (0..1), d4 = float4 chunk (0..31).
    {
        const int qg = (w >> 1) * 8;        // 0 or 8
        const int dh = w & 1;               // 0 or 1
        const int jj = lane >> 5;           // 0..1
        const int d4 = lane & 31;           // 0..31
        const float* Vq = V + ((size_t)b * NN + prev + jj * 32) * DD + dh * 128 + d4 * 4;

        float4 o[8];
        #pragma unroll
        for (int t = 0; t < 8; ++t) o[t] = make_float4(0.f, 0.f, 0.f, 0.f);

        #pragma unroll
        for (int k4 = 0; k4 < 8; ++k4) {    // 32 rows per jj-half, 4 at a time
            float4 vv0 = *(const float4*)(Vq + (size_t)(k4 * 4 + 0) * DD);
            float4 vv1 = *(const float4*)(Vq + (size_t)(k4 * 4 + 1) * DD);
            float4 vv2 = *(const float4*)(Vq + (size_t)(k4 * 4 + 2) * DD);
            float4 vv3 = *(const float4*)(Vq + (size_t)(k4 * 4 + 3) * DD);
            #pragma unroll
            for (int t = 0; t < 8; ++t) {
                // 2 addresses across the wave (jj) -> 2-way broadcast, free
                float4 p4 = *(const float4*)&p_lds[qg + t][jj * 32 + k4 * 4];
                o[t].x = fmaf(p4.x, vv0.x, fmaf(p4.y, vv1.x, fmaf(p4.z, vv2.x, fmaf(p4.w, vv3.x, o[t].x))));
                o[t].y = fmaf(p4.x, vv0.y, fmaf(p4.y, vv1.y, fmaf(p4.z, vv2.y, fmaf(p4.w, vv3.y, o[t].y))));
                o[t].z = fmaf(p4.x, vv0.z, fmaf(p4.y, vv1.z, fmaf(p4.z, vv2.z, fmaf(p4.w, vv3.z, o[t].z))));
                o[t].w = fmaf(p4.x, vv0.w, fmaf(p4.y, vv1.w, fmaf(p4.z, vv2.w, fmaf(p4.w, vv3.w, o[t].w))));
            }
        }

        // reduce the two row-halves (lane ^ 32)
        #pragma unroll
        for (int t = 0; t < 8; ++t) {
            o[t].x += __shfl_xor(o[t].x, 32);
            o[t].y += __shfl_xor(o[t].y, 32);
            o[t].z += __shfl_xor(o[t].z, 32);
            o[t].w += __shfl_xor(o[t].w, 32);
        }

        // store: jj group stores rows qg + jj*4 + tt; acc index compile-time,
        // jj-select via cndmask. Two contiguous 512B segments per store.
        #pragma unroll
        for (int tt = 0; tt < 4; ++tt) {
            float4 ov;
            ov.x = jj ? o[tt + 4].x : o[tt].x;
            ov.y = jj ? o[tt + 4].y : o[tt].y;
            ov.z = jj ? o[tt + 4].z : o[tt].z;
            ov.w = jj ? o[tt + 4].w : o[tt].w;
            float* Rp = Rout + ((size_t)b * TT + t0 + qg + jj * 4 + tt) * (2 * DD)
                        + dh * 128 + d4 * 4;
            nts4(Rp, ov);
        }
    }
}

extern "C" void kernel_launch(void* const* d_in, const int* in_sizes, int n_in,
                              void* d_out, int out_size, void* d_ws, size_t ws_size,
                              hipStream_t stream) {
    const float* Q = (const float*)d_in[0];
    const float* K = (const float*)d_in[1];
    const float* V = (const float*)d_in[2];
    const int* prev = (const int*)d_in[3];
    float* out = (float*)d_out;

    // single launch: 240 zero-streaming blocks first, then 1024 attn blocks
    attn_v18<<<NZ + BB * TT / TBLK, NT, 0, stream>>>(Q, K, V, prev, out);
}